// Round 6
// baseline (9156.418 us; speedup 1.0000x reference)
//
#include <hip/hip_runtime.h>
#include <hip/hip_bf16.h>

typedef __bf16 bf16;
typedef __bf16 bf16x8 __attribute__((ext_vector_type(8)));
typedef float  f32x4  __attribute__((ext_vector_type(4)));

// ---------------------------------------------------------------------------
// f32 -> bf16 straight cast, 8 elems/thread
__global__ __launch_bounds__(256) void cast_f32_bf16(const float* __restrict__ in,
                                                     bf16* __restrict__ out) {
    size_t i = ((size_t)blockIdx.x * blockDim.x + threadIdx.x) * 8;
    float4 a = *(const float4*)(in + i);
    float4 b = *(const float4*)(in + i + 4);
    bf16x8 o;
    o[0] = (bf16)a.x; o[1] = (bf16)a.y; o[2] = (bf16)a.z; o[3] = (bf16)a.w;
    o[4] = (bf16)b.x; o[5] = (bf16)b.y; o[6] = (bf16)b.z; o[7] = (bf16)b.w;
    *(bf16x8*)(out + i) = o;
}

// ---------------------------------------------------------------------------
// W[R][C] f32 -> Wt[C][R] bf16
__global__ __launch_bounds__(256) void transpose_cast(const float* __restrict__ in,
                                                      bf16* __restrict__ out,
                                                      int R, int C) {
    __shared__ float tile[32][33];
    int c0 = blockIdx.x * 32, r0 = blockIdx.y * 32;
    int tx = threadIdx.x & 31, ty = threadIdx.x >> 5;
    #pragma unroll
    for (int i = 0; i < 32; i += 8)
        tile[ty + i][tx] = in[(size_t)(r0 + ty + i) * C + c0 + tx];
    __syncthreads();
    #pragma unroll
    for (int i = 0; i < 32; i += 8)
        out[(size_t)(c0 + ty + i) * R + r0 + tx] = (bf16)tile[tx][ty + i];
}

// ---------------------------------------------------------------------------
// C[M][N] = A[M][K] @ B[K][N] (+bias). A bf16 row-major, Bt = B^T bf16 [N][K].
template<bool BF16_OUT, bool HAS_BIAS>
__global__ __launch_bounds__(256) void gemm128(const bf16* __restrict__ A,
                                               const bf16* __restrict__ Bt,
                                               const float* __restrict__ bias,
                                               void* __restrict__ Cout,
                                               int M, int N, int K) {
    __shared__ bf16 sA[128][72];
    __shared__ bf16 sB[128][72];
    const int tid = threadIdx.x, lane = tid & 63, w = tid >> 6;
    const int wr = w >> 1, wc = w & 1;
    const int m0 = blockIdx.y * 128, n0 = blockIdx.x * 128;
    const int ml = lane & 15, kb = (lane >> 4) * 8;

    f32x4 acc[4][4] = {};

    const bf16* Ab = A  + (size_t)m0 * K;
    const bf16* Bb = Bt + (size_t)n0 * K;

    for (int kc = 0; kc < K; kc += 64) {
        #pragma unroll
        for (int i = 0; i < 4; ++i) {
            int c = tid + 256 * i;
            int row = c >> 3, col = (c & 7) * 8;
            *(uint4*)&sA[row][col] = *(const uint4*)(Ab + (size_t)row * K + kc + col);
            *(uint4*)&sB[row][col] = *(const uint4*)(Bb + (size_t)row * K + kc + col);
        }
        __syncthreads();
        #pragma unroll
        for (int ks = 0; ks < 2; ++ks) {
            bf16x8 af[4], bfr[4];
            #pragma unroll
            for (int i = 0; i < 4; ++i)
                af[i] = *(const bf16x8*)&sA[wr * 64 + i * 16 + ml][ks * 32 + kb];
            #pragma unroll
            for (int i = 0; i < 4; ++i)
                bfr[i] = *(const bf16x8*)&sB[wc * 64 + i * 16 + ml][ks * 32 + kb];
            #pragma unroll
            for (int mi = 0; mi < 4; ++mi)
                #pragma unroll
                for (int ni = 0; ni < 4; ++ni)
                    acc[mi][ni] = __builtin_amdgcn_mfma_f32_16x16x32_bf16(
                        af[mi], bfr[ni], acc[mi][ni], 0, 0, 0);
        }
        __syncthreads();
    }
    const int rbase = (lane >> 4) * 4;
    #pragma unroll
    for (int mi = 0; mi < 4; ++mi) {
        #pragma unroll
        for (int ni = 0; ni < 4; ++ni) {
            int col = n0 + wc * 64 + ni * 16 + ml;
            float bv = HAS_BIAS ? bias[col] : 0.f;
            #pragma unroll
            for (int r = 0; r < 4; ++r) {
                int row = m0 + wr * 64 + mi * 16 + rbase + r;
                float v = acc[mi][ni][r] + bv;
                if constexpr (BF16_OUT)
                    ((bf16*)Cout)[(size_t)row * N + col] = (bf16)v;
                else
                    ((float*)Cout)[(size_t)row * N + col] = v;
            }
        }
    }
}

// ---------------------------------------------------------------------------
// [64 rows x 1024] @ [1024 x 48-col LDS slice] -> acc[3] per thread.
// h rows are at FRESH addresses each step -> plain CACHED loads (L2-shared
// across the XCD's blocks). Producer wrote them sc write-through to MALL.
__device__ __forceinline__ void mm_step(const char* sW, const bf16* hsrc,
                                        int myrow, int kb, int ml, f32x4 acc[3]) {
    const char* rowp = (const char*)(hsrc + (size_t)myrow * 1024) + kb * 2;
    #pragma unroll
    for (int half = 0; half < 2; ++half) {
        uint4 hq[16];
        #pragma unroll
        for (int ks = 0; ks < 16; ++ks)
            hq[ks] = *(const uint4*)(rowp + (half * 16 + ks) * 64);
        #pragma unroll
        for (int ks = 0; ks < 16; ++ks) {
            bf16x8 af = __builtin_bit_cast(bf16x8, hq[ks]);
            #pragma unroll
            for (int g = 0; g < 3; ++g) {
                int brow = g * 16 + ml;
                int addr = brow * 2048 + ((half * 16 + ks) * 32 + kb) * 2;
                addr ^= (brow & 7) << 4;
                bf16x8 bw = *(const bf16x8*)(sW + addr);
                acc[g] = __builtin_amdgcn_mfma_f32_16x16x32_bf16(af, bw, acc[g], 0, 0, 0);
            }
        }
    }
}

__device__ __forceinline__ void store_pair_sc(bf16* base, size_t idx,
                                              unsigned short v, int ml) {
    unsigned nb = (unsigned)__shfl_xor((int)(unsigned)v, 1, 64);
    if ((ml & 1) == 0) {
        unsigned pk = (unsigned)v | (nb << 16);
        __hip_atomic_store((unsigned*)(base + idx), pk,
                           __ATOMIC_RELAXED, __HIP_MEMORY_SCOPE_AGENT);
    }
}

// Uniform-address sc poll of a per-step arrival counter.
__device__ __forceinline__ void wait_ge(unsigned* ctr, unsigned tgt) {
    while (__hip_atomic_load(ctr, __ATOMIC_RELAXED, __HIP_MEMORY_SCOPE_AGENT) < tgt)
        __builtin_amdgcn_s_sleep(1);
    asm volatile("" ::: "memory");
}

__device__ __forceinline__ void arrive(unsigned* ctr, int lane) {
    asm volatile("s_waitcnt vmcnt(0)" ::: "memory");
    if (lane == 0)
        __hip_atomic_fetch_add(ctr, 1u, __ATOMIC_RELAXED, __HIP_MEMORY_SCOPE_AGENT);
}

// ---------------------------------------------------------------------------
// Fused 2-layer GRU pipeline, 192 blocks x 256 thr (4 waves, 16 batch rows ea):
//  role 0 (blk 0..63):   layer-1 scan -> h1[t] (fresh addresses, 512 slots)
//  role 1 (blk 64..127): gx2[t] = h1[t] @ W2f  -> 16-slot ring (sc both sides)
//  role 2 (blk 128..191):layer-2 scan -> hs2[t] (fresh addresses)
// Sync: done{1,2,3}[t] arrival counters (256 wave-arrivals each), sc-polled.
__global__ __launch_bounds__(256, 1) void gru_fused(
    const bf16* __restrict__ WH1, const bf16* __restrict__ WH2,
    const bf16* __restrict__ W2fT, const bf16* __restrict__ gx1,
    const float* __restrict__ pad, const float* __restrict__ b2,
    bf16* __restrict__ h1,       // [512][64][1024]
    bf16* __restrict__ gx2ring,  // 16 x [64][3072]
    bf16* __restrict__ hs2,      // [512][64][1024]
    unsigned* __restrict__ done1, unsigned* __restrict__ done2,
    unsigned* __restrict__ done3) {
    extern __shared__ __align__(16) char sW[];   // 48 x 2048 B, swizzled

    const int tid = threadIdx.x, lane = tid & 63, wv = tid >> 6;
    const int role = blockIdx.x >> 6, jg = blockIdx.x & 63;
    const int j0 = jg * 16;
    const int ml = lane & 15, kb = (lane >> 4) * 8;
    const int rbase = (lane >> 4) * 4;
    const int myrow = wv * 16 + ml;
    const int bbase = wv * 16 + rbase;
    const int jml = j0 + ml;

    // ---- load this role's 48x1024 weight slice into LDS (rows gate*16+j)
    const bf16* Wsrc = (role == 0) ? WH1 : (role == 1) ? W2fT : WH2;
    #pragma unroll 1
    for (int i = 0; i < 24; ++i) {
        int c = tid + 256 * i;
        int rr = c >> 7;
        int off = (c & 127) * 16;
        int gate = rr >> 4, j = rr & 15;
        const bf16* src = Wsrc + (size_t)(gate * 1024 + j0 + j) * 1024 + off / 2;
        *(uint4*)(sW + rr * 2048 + (off ^ ((rr & 7) << 4))) = *(const uint4*)src;
    }
    __syncthreads();   // sW read-only afterwards; waves free-run

    if (role == 0) {
        // ================= layer-1 scan =================
        float hreg[4] = {0.f, 0.f, 0.f, 0.f};
        float gxv[12]; float4 pv;
        #pragma unroll
        for (int r = 0; r < 4; ++r) {
            size_t b = (size_t)(bbase + r);
            gxv[r * 3 + 0] = (float)gx1[b * 3072 + jml];
            gxv[r * 3 + 1] = (float)gx1[b * 3072 + 1024 + jml];
            gxv[r * 3 + 2] = (float)gx1[b * 3072 + 2048 + jml];
        }
        pv = *(const float4*)(pad + bbase);

        for (int t = 0; t < 512; ++t) {
            f32x4 acc[3] = {};
            if (t > 0) {
                wait_ge(done1 + (t - 1), 256u);
                mm_step(sW, h1 + (size_t)(t - 1) * 65536, myrow, kb, ml, acc);
            }
            unsigned short hpk[4];
            #pragma unroll
            for (int r = 0; r < 4; ++r) {
                float rr = 1.f / (1.f + __expf(-(gxv[r * 3 + 0] + acc[0][r])));
                float zz = 1.f / (1.f + __expf(-(gxv[r * 3 + 1] + acc[1][r])));
                float nn = tanhf(gxv[r * 3 + 2] + rr * acc[2][r]);
                float hold = hreg[r];
                float hn = (1.f - zz) * nn + zz * hold;
                float p = (r == 0) ? pv.x : (r == 1) ? pv.y : (r == 2) ? pv.z : pv.w;
                hn = p * hold + (1.f - p) * hn;
                hreg[r] = hn;
                hpk[r] = __builtin_bit_cast(unsigned short, (bf16)hn);
            }
            bf16* hst = h1 + (size_t)t * 65536;
            #pragma unroll
            for (int r = 0; r < 4; ++r)
                store_pair_sc(hst, (size_t)(bbase + r) * 1024 + jml, hpk[r], ml);
            arrive(done1 + t, lane);
            {   // prefetch gx1 + pad for t+1 (cached; fresh-enough lines)
                int tn = (t < 511) ? t + 1 : 511;
                const bf16* gxt = gx1 + (size_t)tn * 64 * 3072;
                #pragma unroll
                for (int r = 0; r < 4; ++r) {
                    size_t b = (size_t)(bbase + r);
                    gxv[r * 3 + 0] = (float)gxt[b * 3072 + jml];
                    gxv[r * 3 + 1] = (float)gxt[b * 3072 + 1024 + jml];
                    gxv[r * 3 + 2] = (float)gxt[b * 3072 + 2048 + jml];
                }
                pv = *(const float4*)(pad + tn * 64 + bbase);
            }
        }
    } else if (role == 1) {
        // ================= gx2 producer =================
        for (int t = 0; t < 512; ++t) {
            wait_ge(done1 + t, 256u);
            if (t >= 16) wait_ge(done3 + (t - 16), 256u);   // ring back-pressure
            f32x4 acc[3] = {};
            mm_step(sW, h1 + (size_t)t * 65536, myrow, kb, ml, acc);
            bf16* dst = gx2ring + (size_t)(t & 15) * 196608;
            #pragma unroll
            for (int r = 0; r < 4; ++r)
                #pragma unroll
                for (int g = 0; g < 3; ++g) {
                    unsigned short v = __builtin_bit_cast(unsigned short, (bf16)acc[g][r]);
                    store_pair_sc(dst, (size_t)(bbase + r) * 3072 + g * 1024 + jml, v, ml);
                }
            arrive(done2 + t, lane);
        }
    } else {
        // ================= layer-2 scan =================
        float b2v[3] = {b2[jml], b2[1024 + jml], b2[2048 + jml]};
        float hreg[4] = {0.f, 0.f, 0.f, 0.f};
        float4 pv = *(const float4*)(pad + bbase);

        for (int t = 0; t < 512; ++t) {
            wait_ge(done2 + t, 256u);
            // gx2 slice: small sc scalar loads (ring addresses are reused)
            const bf16* gsl = gx2ring + (size_t)(t & 15) * 196608;
            unsigned short gu[12];
            #pragma unroll
            for (int r = 0; r < 4; ++r)
                #pragma unroll
                for (int g = 0; g < 3; ++g)
                    gu[r * 3 + g] = __hip_atomic_load(
                        (const unsigned short*)(gsl + (size_t)(bbase + r) * 3072 + g * 1024 + jml),
                        __ATOMIC_RELAXED, __HIP_MEMORY_SCOPE_AGENT);
            f32x4 acc[3] = {};
            if (t > 0) {
                wait_ge(done3 + (t - 1), 256u);
                mm_step(sW, hs2 + (size_t)(t - 1) * 65536, myrow, kb, ml, acc);
            }
            unsigned short hpk[4];
            #pragma unroll
            for (int r = 0; r < 4; ++r) {
                float gr = (float)__builtin_bit_cast(bf16, gu[r * 3 + 0]) + b2v[0];
                float gz = (float)__builtin_bit_cast(bf16, gu[r * 3 + 1]) + b2v[1];
                float gn = (float)__builtin_bit_cast(bf16, gu[r * 3 + 2]) + b2v[2];
                float rr = 1.f / (1.f + __expf(-(gr + acc[0][r])));
                float zz = 1.f / (1.f + __expf(-(gz + acc[1][r])));
                float nn = tanhf(gn + rr * acc[2][r]);
                float hold = hreg[r];
                float hn = (1.f - zz) * nn + zz * hold;
                float p = (r == 0) ? pv.x : (r == 1) ? pv.y : (r == 2) ? pv.z : pv.w;
                hn = p * hold + (1.f - p) * hn;
                hreg[r] = hn;
                hpk[r] = __builtin_bit_cast(unsigned short, (bf16)hn);
            }
            bf16* hst = hs2 + (size_t)t * 65536;
            #pragma unroll
            for (int r = 0; r < 4; ++r)
                store_pair_sc(hst, (size_t)(bbase + r) * 1024 + jml, hpk[r], ml);
            arrive(done3 + t, lane);
            int tn = (t < 511) ? t + 1 : 511;
            pv = *(const float4*)(pad + tn * 64 + bbase);
        }
    }
}

// ---------------------------------------------------------------------------
extern "C" void kernel_launch(void* const* d_in, const int* in_sizes, int n_in,
                              void* d_out, int out_size, void* d_ws, size_t ws_size,
                              hipStream_t stream) {
    const float* x    = (const float*)d_in[0];
    const float* pad  = (const float*)d_in[1];
    const float* Wih1 = (const float*)d_in[2];
    const float* Whh1 = (const float*)d_in[3];
    const float* b1   = (const float*)d_in[4];
    const float* Who1 = (const float*)d_in[5];
    const float* Wih2 = (const float*)d_in[6];
    const float* Whh2 = (const float*)d_in[7];
    const float* b2   = (const float*)d_in[8];
    const float* Who2 = (const float*)d_in[9];
    float* out_f = (float*)d_out;

    char* p = (char*)d_ws;
    bf16* xb      = (bf16*)p; p += (size_t)32768 * 1024 * 2;  //  64MB
    bf16* gxb     = (bf16*)p; p += (size_t)32768 * 3072 * 2;  // 192MB
    bf16* h1      = (bf16*)p; p += (size_t)32768 * 1024 * 2;  //  64MB
    bf16* hs2     = (bf16*)p; p += (size_t)32768 * 1024 * 2;  //  64MB
    bf16* gx2ring = (bf16*)p; p += (size_t)16 * 196608 * 2;   //   6MB
    bf16* WT1     = (bf16*)p; p += (size_t)3072 * 1024 * 2;   //   6MB
    bf16* who1b   = (bf16*)p; p += (size_t)1024 * 1024 * 2;   //   2MB
    bf16* W2fT    = (bf16*)p; p += (size_t)3072 * 1024 * 2;   //   6MB
    bf16* WH1     = (bf16*)p; p += (size_t)3072 * 1024 * 2;   //   6MB
    bf16* WH2     = (bf16*)p; p += (size_t)3072 * 1024 * 2;   //   6MB
    unsigned* flags = (unsigned*)p; p += 8192;
    unsigned* done1 = flags, * done2 = flags + 512, * done3 = flags + 1024;

    hipFuncSetAttribute((const void*)gru_fused,
                        hipFuncAttributeMaxDynamicSharedMemorySize, 131072);

    // 1. x -> bf16
    cast_f32_bf16<<<16384, 256, 0, stream>>>(x, xb);
    // 2. gx1 = x @ Wih1 + b1
    transpose_cast<<<dim3(96, 32), 256, 0, stream>>>(Wih1, WT1, 1024, 3072);
    gemm128<true, true><<<dim3(24, 256), 256, 0, stream>>>(
        xb, WT1, b1, gxb, 32768, 3072, 1024);
    // 3. W2fT = (Who1 @ Wih2)^T : row-major (Wih2^T) @ (Who1)  -> [3072][1024]
    transpose_cast<<<dim3(96, 32), 256, 0, stream>>>(Wih2, WT1, 1024, 3072);
    cast_f32_bf16<<<512, 256, 0, stream>>>(Who1, who1b);
    gemm128<true, false><<<dim3(8, 24), 256, 0, stream>>>(
        WT1, who1b, nullptr, W2fT, 3072, 1024, 1024);
    // 4. recurrent weights
    transpose_cast<<<dim3(96, 32), 256, 0, stream>>>(Whh1, WH1, 1024, 3072);
    transpose_cast<<<dim3(96, 32), 256, 0, stream>>>(Whh2, WH2, 1024, 3072);
    // 5. Who2T (WT1 reuse is safe in stream order)
    transpose_cast<<<dim3(32, 32), 256, 0, stream>>>(Who2, WT1, 1024, 1024);
    // 6. fused pipelined scan
    hipMemsetAsync(flags, 0, 8192, stream);
    gru_fused<<<192, 256, 98304, stream>>>(WH1, WH2, W2fT, gxb, pad, b2,
                                           h1, gx2ring, hs2, done1, done2, done3);
    // 7. out = hs2 @ Who2
    gemm128<false, false><<<dim3(8, 256), 256, 0, stream>>>(
        hs2, WT1, nullptr, out_f, 32768, 1024, 1024);
}

// Round 7
// 6810.562 us; speedup vs baseline: 1.3444x; 1.3444x over previous
//
#include <hip/hip_runtime.h>
#include <hip/hip_bf16.h>

typedef __bf16 bf16;
typedef __bf16 bf16x8 __attribute__((ext_vector_type(8)));
typedef float  f32x4  __attribute__((ext_vector_type(4)));

// ---------------------------------------------------------------------------
// f32 -> bf16 straight cast, 8 elems/thread
__global__ __launch_bounds__(256) void cast_f32_bf16(const float* __restrict__ in,
                                                     bf16* __restrict__ out) {
    size_t i = ((size_t)blockIdx.x * blockDim.x + threadIdx.x) * 8;
    float4 a = *(const float4*)(in + i);
    float4 b = *(const float4*)(in + i + 4);
    bf16x8 o;
    o[0] = (bf16)a.x; o[1] = (bf16)a.y; o[2] = (bf16)a.z; o[3] = (bf16)a.w;
    o[4] = (bf16)b.x; o[5] = (bf16)b.y; o[6] = (bf16)b.z; o[7] = (bf16)b.w;
    *(bf16x8*)(out + i) = o;
}

// ---------------------------------------------------------------------------
// W[R][C] f32 -> Wt[C][R] bf16
__global__ __launch_bounds__(256) void transpose_cast(const float* __restrict__ in,
                                                      bf16* __restrict__ out,
                                                      int R, int C) {
    __shared__ float tile[32][33];
    int c0 = blockIdx.x * 32, r0 = blockIdx.y * 32;
    int tx = threadIdx.x & 31, ty = threadIdx.x >> 5;
    #pragma unroll
    for (int i = 0; i < 32; i += 8)
        tile[ty + i][tx] = in[(size_t)(r0 + ty + i) * C + c0 + tx];
    __syncthreads();
    #pragma unroll
    for (int i = 0; i < 32; i += 8)
        out[(size_t)(c0 + ty + i) * R + r0 + tx] = (bf16)tile[tx][ty + i];
}

// ---------------------------------------------------------------------------
// C[M][N] = A[M][K] @ B[K][N] (+bias). A bf16 row-major, Bt = B^T bf16 [N][K].
template<bool BF16_OUT, bool HAS_BIAS>
__global__ __launch_bounds__(256) void gemm128(const bf16* __restrict__ A,
                                               const bf16* __restrict__ Bt,
                                               const float* __restrict__ bias,
                                               void* __restrict__ Cout,
                                               int M, int N, int K) {
    __shared__ bf16 sA[128][72];
    __shared__ bf16 sB[128][72];
    const int tid = threadIdx.x, lane = tid & 63, w = tid >> 6;
    const int wr = w >> 1, wc = w & 1;
    const int m0 = blockIdx.y * 128, n0 = blockIdx.x * 128;
    const int ml = lane & 15, kb = (lane >> 4) * 8;

    f32x4 acc[4][4] = {};

    const bf16* Ab = A  + (size_t)m0 * K;
    const bf16* Bb = Bt + (size_t)n0 * K;

    for (int kc = 0; kc < K; kc += 64) {
        #pragma unroll
        for (int i = 0; i < 4; ++i) {
            int c = tid + 256 * i;
            int row = c >> 3, col = (c & 7) * 8;
            *(uint4*)&sA[row][col] = *(const uint4*)(Ab + (size_t)row * K + kc + col);
            *(uint4*)&sB[row][col] = *(const uint4*)(Bb + (size_t)row * K + kc + col);
        }
        __syncthreads();
        #pragma unroll
        for (int ks = 0; ks < 2; ++ks) {
            bf16x8 af[4], bfr[4];
            #pragma unroll
            for (int i = 0; i < 4; ++i)
                af[i] = *(const bf16x8*)&sA[wr * 64 + i * 16 + ml][ks * 32 + kb];
            #pragma unroll
            for (int i = 0; i < 4; ++i)
                bfr[i] = *(const bf16x8*)&sB[wc * 64 + i * 16 + ml][ks * 32 + kb];
            #pragma unroll
            for (int mi = 0; mi < 4; ++mi)
                #pragma unroll
                for (int ni = 0; ni < 4; ++ni)
                    acc[mi][ni] = __builtin_amdgcn_mfma_f32_16x16x32_bf16(
                        af[mi], bfr[ni], acc[mi][ni], 0, 0, 0);
        }
        __syncthreads();
    }
    const int rbase = (lane >> 4) * 4;
    #pragma unroll
    for (int mi = 0; mi < 4; ++mi) {
        #pragma unroll
        for (int ni = 0; ni < 4; ++ni) {
            int col = n0 + wc * 64 + ni * 16 + ml;
            float bv = HAS_BIAS ? bias[col] : 0.f;
            #pragma unroll
            for (int r = 0; r < 4; ++r) {
                int row = m0 + wr * 64 + mi * 16 + rbase + r;
                float v = acc[mi][ni][r] + bv;
                if constexpr (BF16_OUT)
                    ((bf16*)Cout)[(size_t)row * N + col] = (bf16)v;
                else
                    ((float*)Cout)[(size_t)row * N + col] = v;
            }
        }
    }
}

// ---------------------------------------------------------------------------
// Persistent GRU scan, round-4 structure + CACHED h reads.
// 128 blocks = 2 batch-halves x 64 col-groups, 128 threads = 2 free-running
// waves (wave wv owns batch rows b0+wv*16..+15). Whh slice (48x1024 bf16,
// 96KB) in LDS the whole scan. hs[t] is a fresh address each step (no WAR):
// producer stores sc write-through (lands at MALL), drains vmcnt, stores its
// flag; consumer polls its 64-flag group with ONE coalesced 64-lane sc load,
// then reads hs[t-1] with plain CACHED dwordx4 loads -> per XCD only the
// first block misses to MALL, the rest hit L2 (traffic 8MB/step -> ~1MB/step).
// Safety: lines are fresh addresses; dispatch-start acquire invalidated L2s.
__global__ __launch_bounds__(128, 1) void gru_scan(const bf16*  __restrict__ WhhT,  // [3072][1024]
                                                   const bf16*  __restrict__ gx,    // [512*64][3072]
                                                   const float* __restrict__ pad,   // [512][64]
                                                   bf16*        __restrict__ hs,    // [512*64][1024]
                                                   unsigned*    __restrict__ flags) {
    extern __shared__ __align__(16) char sW[];   // 48 rows x 2048 B, swizzled

    const int tid  = threadIdx.x;
    const int lane = tid & 63, wv = tid >> 6;
    const int jg = blockIdx.x & 63;    // column group (16 cols)
    const int bh = blockIdx.x >> 6;    // batch half (32 rows)
    const int j0 = jg * 16, b0 = bh * 32;
    const int ml = lane & 15, kb = (lane >> 4) * 8;
    const int rbase = (lane >> 4) * 4;

    unsigned* fgrp = flags + (bh * 2 + wv) * 64;   // this wave's flag group

    // ---- load Whh slice into LDS once
    for (int i = 0; i < 48; ++i) {
        int c   = tid + 128 * i;
        int rr  = c >> 7;              // 0..47
        int off = (c & 127) * 16;
        int gate = rr >> 4, j = rr & 15;
        const bf16* src = WhhT + (size_t)(gate * 1024 + j0 + j) * 1024 + off / 2;
        *(uint4*)(sW + rr * 2048 + (off ^ ((rr & 7) << 4))) = *(const uint4*)src;
    }
    __syncthreads();   // sW read-only afterwards; waves free-run from here

    const int myrow = b0 + wv * 16 + ml;   // h row this thread reads (A frag)
    const int jml   = j0 + ml;             // output col
    const int bbase = b0 + wv * 16 + rbase;

    float hreg[4] = {0.f, 0.f, 0.f, 0.f};
    float gxv[12];
    float4 pv;
    {   // prefetch gx + pad for t=0
        #pragma unroll
        for (int r = 0; r < 4; ++r) {
            size_t b = (size_t)(bbase + r);
            gxv[r * 3 + 0] = (float)gx[b * 3072 + jml];
            gxv[r * 3 + 1] = (float)gx[b * 3072 + 1024 + jml];
            gxv[r * 3 + 2] = (float)gx[b * 3072 + 2048 + jml];
        }
        pv = *(const float4*)(pad + bbase);
    }

    for (int t = 0; t < 512; ++t) {
        f32x4 acc[3] = {};

        if (t > 0) {
            // ---- wait for all 64 producer slices of step t-1 (one vec load)
            unsigned tgt = (unsigned)t;
            while (true) {
                unsigned f = __hip_atomic_load(fgrp + lane, __ATOMIC_RELAXED,
                                               __HIP_MEMORY_SCOPE_AGENT);
                if (__all((int)(f >= tgt))) break;
                __builtin_amdgcn_s_sleep(1);
            }
            asm volatile("" ::: "memory");   // no hoisting of h loads above poll

            const bf16* hprev = hs + (size_t)(t - 1) * 65536;
            const char* rowp = (const char*)(hprev + (size_t)myrow * 1024) + kb * 2;
            #pragma unroll
            for (int half = 0; half < 2; ++half) {
                uint4 hq[16];
                #pragma unroll
                for (int ks = 0; ks < 16; ++ks) {
                    const char* ap = rowp + (half * 16 + ks) * 64;
                    asm volatile("global_load_dwordx4 %0, %1, off"
                                 : "=v"(hq[ks]) : "v"(ap) : "memory");
                }
                asm volatile("s_waitcnt vmcnt(0)" ::: "memory");
                __builtin_amdgcn_sched_barrier(0);
                #pragma unroll
                for (int ks = 0; ks < 16; ++ks) {
                    bf16x8 af = __builtin_bit_cast(bf16x8, hq[ks]);
                    #pragma unroll
                    for (int g = 0; g < 3; ++g) {
                        int brow = g * 16 + ml;
                        int addr = brow * 2048 + ((half * 16 + ks) * 32 + kb) * 2;
                        addr ^= (brow & 7) << 4;
                        bf16x8 bw = *(const bf16x8*)(sW + addr);
                        acc[g] = __builtin_amdgcn_mfma_f32_16x16x32_bf16(af, bw, acc[g], 0, 0, 0);
                    }
                }
            }
        }

        // ---- gates + state update (thread owns rows bbase+r, col jml)
        unsigned short hpk[4];
        #pragma unroll
        for (int r = 0; r < 4; ++r) {
            float rr = 1.f / (1.f + __expf(-(gxv[r * 3 + 0] + acc[0][r])));
            float zz = 1.f / (1.f + __expf(-(gxv[r * 3 + 1] + acc[1][r])));
            float nn = tanhf(gxv[r * 3 + 2] + rr * acc[2][r]);
            float hold = hreg[r];
            float hn = (1.f - zz) * nn + zz * hold;
            float p  = (r == 0) ? pv.x : (r == 1) ? pv.y : (r == 2) ? pv.z : pv.w;
            hn = p * hold + (1.f - p) * hn;
            hreg[r] = hn;
            hpk[r] = __builtin_bit_cast(unsigned short, (bf16)hn);
        }

        // ---- store h slice to hs[t] (write-through, pair-packed)
        bf16* hst = hs + (size_t)t * 65536;
        #pragma unroll
        for (int r = 0; r < 4; ++r) {
            unsigned nb = (unsigned)__shfl_xor((int)(unsigned)hpk[r], 1, 64);
            if ((ml & 1) == 0) {
                unsigned v = (unsigned)hpk[r] | (nb << 16);
                __hip_atomic_store((unsigned*)(hst + (size_t)(bbase + r) * 1024 + jml), v,
                                   __ATOMIC_RELAXED, __HIP_MEMORY_SCOPE_AGENT);
            }
        }

        // ---- drain stores, publish flag (relaxed; data already at MALL)
        asm volatile("s_waitcnt vmcnt(0)" ::: "memory");
        if (lane == 0)
            __hip_atomic_store(fgrp + jg, (unsigned)(t + 1),
                               __ATOMIC_RELAXED, __HIP_MEMORY_SCOPE_AGENT);

        // ---- prefetch gx + pad for t+1 (overlaps next step's poll)
        {
            int tn = (t < 511) ? t + 1 : 511;
            const bf16* gxt = gx + (size_t)tn * 64 * 3072;
            #pragma unroll
            for (int r = 0; r < 4; ++r) {
                size_t b = (size_t)(bbase + r);
                gxv[r * 3 + 0] = (float)gxt[b * 3072 + jml];
                gxv[r * 3 + 1] = (float)gxt[b * 3072 + 1024 + jml];
                gxv[r * 3 + 2] = (float)gxt[b * 3072 + 2048 + jml];
            }
            pv = *(const float4*)(pad + tn * 64 + bbase);
        }
    }
}

// ---------------------------------------------------------------------------
extern "C" void kernel_launch(void* const* d_in, const int* in_sizes, int n_in,
                              void* d_out, int out_size, void* d_ws, size_t ws_size,
                              hipStream_t stream) {
    const float* x    = (const float*)d_in[0];
    const float* pad  = (const float*)d_in[1];
    const float* Wih1 = (const float*)d_in[2];
    const float* Whh1 = (const float*)d_in[3];
    const float* b1   = (const float*)d_in[4];
    const float* Who1 = (const float*)d_in[5];
    const float* Wih2 = (const float*)d_in[6];
    const float* Whh2 = (const float*)d_in[7];
    const float* b2   = (const float*)d_in[8];
    const float* Who2 = (const float*)d_in[9];
    float* out_f = (float*)d_out;

    char* p = (char*)d_ws;
    bf16* xb    = (bf16*)p; p += (size_t)32768 * 1024 * 2;  //  64MB
    bf16* gxb   = (bf16*)p; p += (size_t)32768 * 3072 * 2;  // 192MB (gx1, then gx2)
    bf16* hs1   = (bf16*)p; p += (size_t)32768 * 1024 * 2;  //  64MB
    bf16* hs2   = (bf16*)p; p += (size_t)32768 * 1024 * 2;  //  64MB
    bf16* WT1   = (bf16*)p; p += (size_t)3072 * 1024 * 2;   //   6MB
    bf16* who1b = (bf16*)p; p += (size_t)1024 * 1024 * 2;   //   2MB
    bf16* W2fT  = (bf16*)p; p += (size_t)3072 * 1024 * 2;   //   6MB
    bf16* WH1   = (bf16*)p; p += (size_t)3072 * 1024 * 2;   //   6MB
    bf16* WH2   = (bf16*)p; p += (size_t)3072 * 1024 * 2;   //   6MB
    unsigned* flags = (unsigned*)p; p += 4096;
    unsigned* f1 = flags, * f2 = flags + 512;

    hipFuncSetAttribute((const void*)gru_scan,
                        hipFuncAttributeMaxDynamicSharedMemorySize, 131072);

    // 1. x -> bf16
    cast_f32_bf16<<<16384, 256, 0, stream>>>(x, xb);
    // 2. gx1 = x @ Wih1 + b1
    transpose_cast<<<dim3(96, 32), 256, 0, stream>>>(Wih1, WT1, 1024, 3072);
    gemm128<true, true><<<dim3(24, 256), 256, 0, stream>>>(
        xb, WT1, b1, gxb, 32768, 3072, 1024);
    // 3. W2fT = (Who1 @ Wih2)^T  (verified r5 recipe)
    transpose_cast<<<dim3(96, 32), 256, 0, stream>>>(Wih2, WT1, 1024, 3072);
    cast_f32_bf16<<<512, 256, 0, stream>>>(Who1, who1b);
    gemm128<true, false><<<dim3(8, 24), 256, 0, stream>>>(
        WT1, who1b, nullptr, W2fT, 3072, 1024, 1024);
    // 4. recurrent weights + flags
    transpose_cast<<<dim3(96, 32), 256, 0, stream>>>(Whh1, WH1, 1024, 3072);
    transpose_cast<<<dim3(96, 32), 256, 0, stream>>>(Whh2, WH2, 1024, 3072);
    hipMemsetAsync(flags, 0, 4096, stream);
    // 5. layer-1 scan
    gru_scan<<<128, 128, 98304, stream>>>(WH1, gxb, pad, hs1, f1);
    // 6. gx2 = hs1 @ W2f + b2 (fused Who1*Wih2 path; overwrites gxb)
    gemm128<true, true><<<dim3(24, 256), 256, 0, stream>>>(
        hs1, W2fT, b2, gxb, 32768, 3072, 1024);
    // 7. layer-2 scan
    gru_scan<<<128, 128, 98304, stream>>>(WH2, gxb, pad, hs2, f2);
    // 8. out = hs2 @ Who2 (f32)
    transpose_cast<<<dim3(32, 32), 256, 0, stream>>>(Who2, WT1, 1024, 1024);
    gemm128<false, false><<<dim3(8, 256), 256, 0, stream>>>(
        hs2, WT1, nullptr, out_f, 32768, 1024, 1024);
}

// Round 8
// 6107.872 us; speedup vs baseline: 1.4991x; 1.1150x over previous
//
#include <hip/hip_runtime.h>
#include <hip/hip_bf16.h>

typedef __bf16 bf16;
typedef __bf16 bf16x8 __attribute__((ext_vector_type(8)));
typedef float  f32x4  __attribute__((ext_vector_type(4)));

// ---------------------------------------------------------------------------
// f32 -> bf16 straight cast, 8 elems/thread
__global__ __launch_bounds__(256) void cast_f32_bf16(const float* __restrict__ in,
                                                     bf16* __restrict__ out) {
    size_t i = ((size_t)blockIdx.x * blockDim.x + threadIdx.x) * 8;
    float4 a = *(const float4*)(in + i);
    float4 b = *(const float4*)(in + i + 4);
    bf16x8 o;
    o[0] = (bf16)a.x; o[1] = (bf16)a.y; o[2] = (bf16)a.z; o[3] = (bf16)a.w;
    o[4] = (bf16)b.x; o[5] = (bf16)b.y; o[6] = (bf16)b.z; o[7] = (bf16)b.w;
    *(bf16x8*)(out + i) = o;
}

// ---------------------------------------------------------------------------
// W[R][C] f32 -> Wt[C][R] bf16
__global__ __launch_bounds__(256) void transpose_cast(const float* __restrict__ in,
                                                      bf16* __restrict__ out,
                                                      int R, int C) {
    __shared__ float tile[32][33];
    int c0 = blockIdx.x * 32, r0 = blockIdx.y * 32;
    int tx = threadIdx.x & 31, ty = threadIdx.x >> 5;
    #pragma unroll
    for (int i = 0; i < 32; i += 8)
        tile[ty + i][tx] = in[(size_t)(r0 + ty + i) * C + c0 + tx];
    __syncthreads();
    #pragma unroll
    for (int i = 0; i < 32; i += 8)
        out[(size_t)(c0 + ty + i) * R + r0 + tx] = (bf16)tile[tx][ty + i];
}

// ---------------------------------------------------------------------------
// C[M][N] = A[M][K] @ B[K][N] (+bias). A bf16 row-major, Bt = B^T bf16 [N][K].
template<bool BF16_OUT, bool HAS_BIAS>
__global__ __launch_bounds__(256) void gemm128(const bf16* __restrict__ A,
                                               const bf16* __restrict__ Bt,
                                               const float* __restrict__ bias,
                                               void* __restrict__ Cout,
                                               int M, int N, int K) {
    __shared__ bf16 sA[128][72];
    __shared__ bf16 sB[128][72];
    const int tid = threadIdx.x, lane = tid & 63, w = tid >> 6;
    const int wr = w >> 1, wc = w & 1;
    const int m0 = blockIdx.y * 128, n0 = blockIdx.x * 128;
    const int ml = lane & 15, kb = (lane >> 4) * 8;

    f32x4 acc[4][4] = {};

    const bf16* Ab = A  + (size_t)m0 * K;
    const bf16* Bb = Bt + (size_t)n0 * K;

    for (int kc = 0; kc < K; kc += 64) {
        #pragma unroll
        for (int i = 0; i < 4; ++i) {
            int c = tid + 256 * i;
            int row = c >> 3, col = (c & 7) * 8;
            *(uint4*)&sA[row][col] = *(const uint4*)(Ab + (size_t)row * K + kc + col);
            *(uint4*)&sB[row][col] = *(const uint4*)(Bb + (size_t)row * K + kc + col);
        }
        __syncthreads();
        #pragma unroll
        for (int ks = 0; ks < 2; ++ks) {
            bf16x8 af[4], bfr[4];
            #pragma unroll
            for (int i = 0; i < 4; ++i)
                af[i] = *(const bf16x8*)&sA[wr * 64 + i * 16 + ml][ks * 32 + kb];
            #pragma unroll
            for (int i = 0; i < 4; ++i)
                bfr[i] = *(const bf16x8*)&sB[wc * 64 + i * 16 + ml][ks * 32 + kb];
            #pragma unroll
            for (int mi = 0; mi < 4; ++mi)
                #pragma unroll
                for (int ni = 0; ni < 4; ++ni)
                    acc[mi][ni] = __builtin_amdgcn_mfma_f32_16x16x32_bf16(
                        af[mi], bfr[ni], acc[mi][ni], 0, 0, 0);
        }
        __syncthreads();
    }
    const int rbase = (lane >> 4) * 4;
    #pragma unroll
    for (int mi = 0; mi < 4; ++mi) {
        #pragma unroll
        for (int ni = 0; ni < 4; ++ni) {
            int col = n0 + wc * 64 + ni * 16 + ml;
            float bv = HAS_BIAS ? bias[col] : 0.f;
            #pragma unroll
            for (int r = 0; r < 4; ++r) {
                int row = m0 + wr * 64 + mi * 16 + rbase + r;
                float v = acc[mi][ni][r] + bv;
                if constexpr (BF16_OUT)
                    ((bf16*)Cout)[(size_t)row * N + col] = (bf16)v;
                else
                    ((float*)Cout)[(size_t)row * N + col] = v;
            }
        }
    }
}

// ---------------------------------------------------------------------------
// [16 rows x 1024] @ [1024 x 48-col LDS slice] -> acc[3] per thread.
// CACHED inline-asm loads, all 32 quads in flight, staged vmcnt(16)/vmcnt(0).
__device__ __forceinline__ void mm_step(const char* sW, const bf16* hsrc,
                                        int myrow, int kb, int ml, f32x4 acc[3]) {
    const char* rowp = (const char*)(hsrc + (size_t)myrow * 1024) + kb * 2;
    uint4 hq[32];
    #pragma unroll
    for (int ks = 0; ks < 32; ++ks)
        asm volatile("global_load_dwordx4 %0, %1, off"
                     : "=v"(hq[ks]) : "v"(rowp + ks * 64) : "memory");
    asm volatile("s_waitcnt vmcnt(16)" ::: "memory");
    __builtin_amdgcn_sched_barrier(0);
    #pragma unroll
    for (int ks = 0; ks < 16; ++ks) {
        bf16x8 af = __builtin_bit_cast(bf16x8, hq[ks]);
        #pragma unroll
        for (int g = 0; g < 3; ++g) {
            int brow = g * 16 + ml;
            int addr = brow * 2048 + (ks * 32 + kb) * 2;
            addr ^= (brow & 7) << 4;
            bf16x8 bw = *(const bf16x8*)(sW + addr);
            acc[g] = __builtin_amdgcn_mfma_f32_16x16x32_bf16(af, bw, acc[g], 0, 0, 0);
        }
    }
    asm volatile("s_waitcnt vmcnt(0)" ::: "memory");
    __builtin_amdgcn_sched_barrier(0);
    #pragma unroll
    for (int ks = 16; ks < 32; ++ks) {
        bf16x8 af = __builtin_bit_cast(bf16x8, hq[ks]);
        #pragma unroll
        for (int g = 0; g < 3; ++g) {
            int brow = g * 16 + ml;
            int addr = brow * 2048 + (ks * 32 + kb) * 2;
            addr ^= (brow & 7) << 4;
            bf16x8 bw = *(const bf16x8*)(sW + addr);
            acc[g] = __builtin_amdgcn_mfma_f32_16x16x32_bf16(af, bw, acc[g], 0, 0, 0);
        }
    }
}

__device__ __forceinline__ void store_pair_sc(bf16* base, size_t idx,
                                              unsigned short v, int ml) {
    unsigned nb = (unsigned)__shfl_xor((int)(unsigned)v, 1, 64);
    if ((ml & 1) == 0) {
        unsigned pk = (unsigned)v | (nb << 16);
        __hip_atomic_store((unsigned*)(base + idx), pk,
                           __ATOMIC_RELAXED, __HIP_MEMORY_SCOPE_AGENT);
    }
}

// coalesced 64-lane poll of one or two flag groups (monotonic counters)
__device__ __forceinline__ void poll1(const unsigned* a, unsigned ta, int lane) {
    while (true) {
        unsigned fa = __hip_atomic_load(a + lane, __ATOMIC_RELAXED, __HIP_MEMORY_SCOPE_AGENT);
        if (__all((int)(fa >= ta))) break;
        __builtin_amdgcn_s_sleep(1);
    }
    asm volatile("" ::: "memory");
}
__device__ __forceinline__ void poll2(const unsigned* a, unsigned ta,
                                      const unsigned* b, unsigned tb, int lane) {
    while (true) {
        unsigned fa = __hip_atomic_load(a + lane, __ATOMIC_RELAXED, __HIP_MEMORY_SCOPE_AGENT);
        unsigned fb = __hip_atomic_load(b + lane, __ATOMIC_RELAXED, __HIP_MEMORY_SCOPE_AGENT);
        if (__all((int)(fa >= ta && fb >= tb))) break;
        __builtin_amdgcn_s_sleep(1);
    }
    asm volatile("" ::: "memory");
}

__device__ __forceinline__ void publish(unsigned* slot, unsigned val, int lane) {
    asm volatile("s_waitcnt vmcnt(0)" ::: "memory");
    if (lane == 0)
        __hip_atomic_store(slot, val, __ATOMIC_RELAXED, __HIP_MEMORY_SCOPE_AGENT);
}

// ---------------------------------------------------------------------------
// Fused 2-layer GRU pipeline, 192 blocks x 256 thr (4 waves = 16 batch rows ea):
//  role 0 (blk 0..63):   layer-1 scan -> h1[t]  (full 512-slot buffer)
//  role 1 (blk 64..127): gx2[t] = h1[t] @ W2f   -> 16-slot ring (sc)
//  role 2 (blk 128..191):layer-2 scan -> hs2[t] (full 512-slot buffer)
// h1/hs2 reads are CACHED (fresh addresses; producers store sc write-through).
// gx2 ring + flags are sc (reused addresses). Per-wave 64-flag groups.
__global__ __launch_bounds__(256, 1) void gru_fused(
    const bf16* __restrict__ WH1, const bf16* __restrict__ WH2,
    const bf16* __restrict__ W2fT, const bf16* __restrict__ gx1,
    const float* __restrict__ pad, const float* __restrict__ b2,
    bf16* __restrict__ h1,       // [512][64][1024]
    bf16* __restrict__ gx2ring,  // 16 x [64][3072]
    bf16* __restrict__ hs2,      // [512][64][1024]
    unsigned* __restrict__ f1, unsigned* __restrict__ f2,
    unsigned* __restrict__ f3) {
    extern __shared__ __align__(16) char sW[];   // 48 x 2048 B, swizzled

    const int tid = threadIdx.x, lane = tid & 63, wv = tid >> 6;
    const int role = blockIdx.x >> 6, jg = blockIdx.x & 63;
    const int j0 = jg * 16;
    const int ml = lane & 15, kb = (lane >> 4) * 8;
    const int rbase = (lane >> 4) * 4;
    const int myrow = wv * 16 + ml;
    const int bbase = wv * 16 + rbase;
    const int jml = j0 + ml;

    // ---- load this role's 48x1024 weight slice into LDS (rows gate*16+j)
    const bf16* Wsrc = (role == 0) ? WH1 : (role == 1) ? W2fT : WH2;
    #pragma unroll 1
    for (int i = 0; i < 24; ++i) {
        int c = tid + 256 * i;
        int rr = c >> 7;
        int off = (c & 127) * 16;
        int gate = rr >> 4, j = rr & 15;
        const bf16* src = Wsrc + (size_t)(gate * 1024 + j0 + j) * 1024 + off / 2;
        *(uint4*)(sW + rr * 2048 + (off ^ ((rr & 7) << 4))) = *(const uint4*)src;
    }
    __syncthreads();   // sW read-only afterwards; waves free-run

    if (role == 0) {
        // ================= layer-1 scan =================
        unsigned* fown = f1 + wv * 64;
        float hreg[4] = {0.f, 0.f, 0.f, 0.f};
        float gxv[12]; float4 pv;
        #pragma unroll
        for (int r = 0; r < 4; ++r) {
            size_t b = (size_t)(bbase + r);
            gxv[r * 3 + 0] = (float)gx1[b * 3072 + jml];
            gxv[r * 3 + 1] = (float)gx1[b * 3072 + 1024 + jml];
            gxv[r * 3 + 2] = (float)gx1[b * 3072 + 2048 + jml];
        }
        pv = *(const float4*)(pad + bbase);

        for (int t = 0; t < 512; ++t) {
            f32x4 acc[3] = {};
            if (t > 0) {
                poll1(fown, (unsigned)t, lane);
                mm_step(sW, h1 + (size_t)(t - 1) * 65536, myrow, kb, ml, acc);
            }
            unsigned short hpk[4];
            #pragma unroll
            for (int r = 0; r < 4; ++r) {
                float rr = 1.f / (1.f + __expf(-(gxv[r * 3 + 0] + acc[0][r])));
                float zz = 1.f / (1.f + __expf(-(gxv[r * 3 + 1] + acc[1][r])));
                float nn = tanhf(gxv[r * 3 + 2] + rr * acc[2][r]);
                float hold = hreg[r];
                float hn = (1.f - zz) * nn + zz * hold;
                float p = (r == 0) ? pv.x : (r == 1) ? pv.y : (r == 2) ? pv.z : pv.w;
                hn = p * hold + (1.f - p) * hn;
                hreg[r] = hn;
                hpk[r] = __builtin_bit_cast(unsigned short, (bf16)hn);
            }
            bf16* hst = h1 + (size_t)t * 65536;
            #pragma unroll
            for (int r = 0; r < 4; ++r)
                store_pair_sc(hst, (size_t)(bbase + r) * 1024 + jml, hpk[r], ml);
            publish(fown + jg, (unsigned)(t + 1), lane);
            {   // prefetch gx1 + pad for t+1 (cached)
                int tn = (t < 511) ? t + 1 : 511;
                const bf16* gxt = gx1 + (size_t)tn * 64 * 3072;
                #pragma unroll
                for (int r = 0; r < 4; ++r) {
                    size_t b = (size_t)(bbase + r);
                    gxv[r * 3 + 0] = (float)gxt[b * 3072 + jml];
                    gxv[r * 3 + 1] = (float)gxt[b * 3072 + 1024 + jml];
                    gxv[r * 3 + 2] = (float)gxt[b * 3072 + 2048 + jml];
                }
                pv = *(const float4*)(pad + tn * 64 + bbase);
            }
        }
    } else if (role == 1) {
        // ================= gx2 producer =================
        unsigned* fsrc = f1 + wv * 64;
        unsigned* fbp  = f3 + wv * 64;
        for (int t = 0; t < 512; ++t) {
            if (t >= 16) poll2(fsrc, (unsigned)(t + 1), fbp, (unsigned)(t - 15), lane);
            else         poll1(fsrc, (unsigned)(t + 1), lane);
            f32x4 acc[3] = {};
            mm_step(sW, h1 + (size_t)t * 65536, myrow, kb, ml, acc);
            bf16* dst = gx2ring + (size_t)(t & 15) * 196608;
            #pragma unroll
            for (int r = 0; r < 4; ++r)
                #pragma unroll
                for (int g = 0; g < 3; ++g) {
                    unsigned short v = __builtin_bit_cast(unsigned short, (bf16)acc[g][r]);
                    store_pair_sc(dst, (size_t)(bbase + r) * 3072 + g * 1024 + jml, v, ml);
                }
            publish(f2 + wv * 64 + jg, (unsigned)(t + 1), lane);
        }
    } else {
        // ================= layer-2 scan =================
        unsigned* fown = f3 + wv * 64;
        unsigned* fgx  = f2 + wv * 64;
        float b2v[3] = {b2[jml], b2[1024 + jml], b2[2048 + jml]};
        float hreg[4] = {0.f, 0.f, 0.f, 0.f};
        float4 pv = *(const float4*)(pad + bbase);

        for (int t = 0; t < 512; ++t) {
            if (t > 0) poll2(fgx, (unsigned)(t + 1), fown, (unsigned)t, lane);
            else       poll1(fgx, 1u, lane);
            // gx2 slice: small sc scalar loads (ring addresses are reused)
            const bf16* gsl = gx2ring + (size_t)(t & 15) * 196608;
            unsigned short gu[12];
            #pragma unroll
            for (int r = 0; r < 4; ++r)
                #pragma unroll
                for (int g = 0; g < 3; ++g)
                    gu[r * 3 + g] = __hip_atomic_load(
                        (const unsigned short*)(gsl + (size_t)(bbase + r) * 3072 + g * 1024 + jml),
                        __ATOMIC_RELAXED, __HIP_MEMORY_SCOPE_AGENT);
            f32x4 acc[3] = {};
            if (t > 0)
                mm_step(sW, hs2 + (size_t)(t - 1) * 65536, myrow, kb, ml, acc);
            unsigned short hpk[4];
            #pragma unroll
            for (int r = 0; r < 4; ++r) {
                float gr = (float)__builtin_bit_cast(bf16, gu[r * 3 + 0]) + b2v[0];
                float gz = (float)__builtin_bit_cast(bf16, gu[r * 3 + 1]) + b2v[1];
                float gn = (float)__builtin_bit_cast(bf16, gu[r * 3 + 2]) + b2v[2];
                float rr = 1.f / (1.f + __expf(-(gr + acc[0][r])));
                float zz = 1.f / (1.f + __expf(-(gz + acc[1][r])));
                float nn = tanhf(gn + rr * acc[2][r]);
                float hold = hreg[r];
                float hn = (1.f - zz) * nn + zz * hold;
                float p = (r == 0) ? pv.x : (r == 1) ? pv.y : (r == 2) ? pv.z : pv.w;
                hn = p * hold + (1.f - p) * hn;
                hreg[r] = hn;
                hpk[r] = __builtin_bit_cast(unsigned short, (bf16)hn);
            }
            bf16* hst = hs2 + (size_t)t * 65536;
            #pragma unroll
            for (int r = 0; r < 4; ++r)
                store_pair_sc(hst, (size_t)(bbase + r) * 1024 + jml, hpk[r], ml);
            publish(fown + jg, (unsigned)(t + 1), lane);
            int tn = (t < 511) ? t + 1 : 511;
            pv = *(const float4*)(pad + tn * 64 + bbase);
        }
    }
}

// ---------------------------------------------------------------------------
extern "C" void kernel_launch(void* const* d_in, const int* in_sizes, int n_in,
                              void* d_out, int out_size, void* d_ws, size_t ws_size,
                              hipStream_t stream) {
    const float* x    = (const float*)d_in[0];
    const float* pad  = (const float*)d_in[1];
    const float* Wih1 = (const float*)d_in[2];
    const float* Whh1 = (const float*)d_in[3];
    const float* b1   = (const float*)d_in[4];
    const float* Who1 = (const float*)d_in[5];
    const float* Wih2 = (const float*)d_in[6];
    const float* Whh2 = (const float*)d_in[7];
    const float* b2   = (const float*)d_in[8];
    const float* Who2 = (const float*)d_in[9];
    float* out_f = (float*)d_out;

    char* p = (char*)d_ws;
    bf16* xb      = (bf16*)p; p += (size_t)32768 * 1024 * 2;  //  64MB
    bf16* gxb     = (bf16*)p; p += (size_t)32768 * 3072 * 2;  // 192MB (gx1)
    bf16* h1      = (bf16*)p; p += (size_t)32768 * 1024 * 2;  //  64MB
    bf16* hs2     = (bf16*)p; p += (size_t)32768 * 1024 * 2;  //  64MB
    bf16* gx2ring = (bf16*)p; p += (size_t)16 * 196608 * 2;   //   6MB
    bf16* WT1     = (bf16*)p; p += (size_t)3072 * 1024 * 2;   //   6MB
    bf16* who1b   = (bf16*)p; p += (size_t)1024 * 1024 * 2;   //   2MB
    bf16* W2fT    = (bf16*)p; p += (size_t)3072 * 1024 * 2;   //   6MB
    bf16* WH1     = (bf16*)p; p += (size_t)3072 * 1024 * 2;   //   6MB
    bf16* WH2     = (bf16*)p; p += (size_t)3072 * 1024 * 2;   //   6MB
    unsigned* flags = (unsigned*)p; p += 8192;
    unsigned* f1 = flags, * f2 = flags + 512, * f3 = flags + 1024;

    hipFuncSetAttribute((const void*)gru_fused,
                        hipFuncAttributeMaxDynamicSharedMemorySize, 131072);

    // 1. x -> bf16
    cast_f32_bf16<<<16384, 256, 0, stream>>>(x, xb);
    // 2. gx1 = x @ Wih1 + b1
    transpose_cast<<<dim3(96, 32), 256, 0, stream>>>(Wih1, WT1, 1024, 3072);
    gemm128<true, true><<<dim3(24, 256), 256, 0, stream>>>(
        xb, WT1, b1, gxb, 32768, 3072, 1024);
    // 3. W2fT = (Who1 @ Wih2)^T  (verified r5 recipe)
    transpose_cast<<<dim3(96, 32), 256, 0, stream>>>(Wih2, WT1, 1024, 3072);
    cast_f32_bf16<<<512, 256, 0, stream>>>(Who1, who1b);
    gemm128<true, false><<<dim3(8, 24), 256, 0, stream>>>(
        WT1, who1b, nullptr, W2fT, 3072, 1024, 1024);
    // 4. recurrent weights; Who2T into WT1 (its last reader is step 3)
    transpose_cast<<<dim3(96, 32), 256, 0, stream>>>(Whh1, WH1, 1024, 3072);
    transpose_cast<<<dim3(96, 32), 256, 0, stream>>>(Whh2, WH2, 1024, 3072);
    transpose_cast<<<dim3(32, 32), 256, 0, stream>>>(Who2, WT1, 1024, 1024);
    hipMemsetAsync(flags, 0, 8192, stream);
    // 5. fused pipelined 2-layer scan
    gru_fused<<<192, 256, 98304, stream>>>(WH1, WH2, W2fT, gxb, pad, b2,
                                           h1, gx2ring, hs2, f1, f2, f3);
    // 6. out = hs2 @ Who2 (f32)
    gemm128<false, false><<<dim3(8, 256), 256, 0, stream>>>(
        hs2, WT1, nullptr, out_f, 32768, 1024, 1024);
}